// Round 9
// baseline (155.198 us; speedup 1.0000x reference)
//
#include <hip/hip_runtime.h>
#include <hip/hip_fp16.h>

// NCC loss, R16: INVERSE-ABLATION PROBE (chain phase), base = R13 (best: 58.5us).
// R15 post-mortem: no pre-barrier vmcnt drain exists for VGPR loads (only
// LDS-visible ops drain); R13's loads already flew across the barrier. R15's
// stage-first order queued 10 ds_writes ahead of the chains' critical
// ds_read_b128s (+680 cyc/macro). Four theories refuted -> measure, don't
// guess: run every chain TWICE (idempotent: same raw inputs, same hsum bytes
// rewritten -> absmax 0.0; asm memory-fence between passes blocks CSE).
// Marginal dur = chain phase's critical-path share.
//   chains critical  -> ~75-85us/dispatch -> optimize chain path next.
//   chains absorbed  -> <62us            -> attack ring/stage next.
// Everything else is R13 verbatim (DC=80, 1 barrier/macro, dbuf raw+hsum).
// Vols: [B=2][D=160][H=192][W=160] fp32. Out: scalar -mean(cc).

#define B_    2
#define D_    160
#define H_    192
#define W_    160
#define HW_   (H_*W_)

// LDS layout (float-word offsets)
#define RS    12                   // raw row stride: 24 taps fp16 = 12 dw, packed
#define SLS   (24*RS)              // 288: raw slice stride
#define FS    (2*SLS)              // 576: raw field stride (2 slices)
#define RAWSZ (5*FS)               // 2880: one raw buffer (5 fields)
#define ZROW  (2*RAWSZ)            // 5760: 16 dw of zeros (A2 OOB-row reads)
#define ZEND  (ZROW + 16)          // 5776: end of zero-init region
#define HSUM0 ZEND                 // 5776: hsum buffer 0 (10 chains x 160)
#define HCS   160                  // per-(slc,f) hsum block: 16 cols x 10
#define HRS   10                   // hsum col stride (16 h fp16 = 8 dw, pad->10)
#define HSZ   (10*HCS)             // 1600: one hsum buffer
#define REDU  (HSUM0 + 2*HSZ)      // 8976
#define SMEM  (REDU + 8)           // 8984 dw = 35.9 KB
#define DC    80                   // z-chunk depth (grid z = 4)
#define ZCH   (D_/DC)              // 2 z-chunks per batch
#define NMAC  ((DC+8)/2)           // 44 macros x 2 slices
#define W3I   (1.0f/729.0f)
#define NTOT  9830400.0f

#if __has_builtin(__builtin_amdgcn_rcpf)
#define RCP(x) __builtin_amdgcn_rcpf(x)
#else
#define RCP(x) (1.0f/(x))
#endif

typedef _Float16 half8 __attribute__((ext_vector_type(8)));
typedef float    f32x4 __attribute__((ext_vector_type(4)));
typedef unsigned u32x2 __attribute__((ext_vector_type(2)));
#define MFMA16(a,b,c) __builtin_amdgcn_mfma_f32_16x16x32_f16((a),(b),(c),0,0,0)

// permlane swaps: a=VDST, b=VSRC, both updated.
#if __has_builtin(__builtin_amdgcn_permlane32_swap)
#define PL32(a,b) do { u32x2 _s = __builtin_amdgcn_permlane32_swap((a),(b),false,false); \
                       (a)=_s[0]; (b)=_s[1]; } while(0)
#else
#define PL32(a,b) asm volatile("s_nop 1\nv_permlane32_swap_b32 %0, %1" : "+v"(a), "+v"(b))
#endif
#if __has_builtin(__builtin_amdgcn_permlane16_swap)
#define PL16(a,b) do { u32x2 _s = __builtin_amdgcn_permlane16_swap((a),(b),false,false); \
                       (a)=_s[0]; (b)=_s[1]; } while(0)
#else
#define PL16(a,b) asm volatile("s_nop 1\nv_permlane16_swap_b32 %0, %1" : "+v"(a), "+v"(b))
#endif

struct __align__(8) HP { __half2 a, b; };   // 4 fp16 = one b64 LDS word-pair

__global__ __launch_bounds__(256, 4) void ncc_fused(const float* __restrict__ gI,
                                                    const float* __restrict__ gJ,
                                                    float* __restrict__ out)
{
  __shared__ __align__(16) float sm[SMEM];
  const int tid  = threadIdx.x;
  const int lane = tid & 63;
  const int Q    = tid >> 6;
  const int n15  = lane & 15;          // MFMA: A-row m / B-col n / D-col
  const int q4   = lane >> 4;          // MFMA: k-group / D-row quad
  const int w0   = blockIdx.x * 16;
  const int h0   = blockIdx.y * 16;
  const int bz   = blockIdx.z;
  const int bb   = bz / ZCH;
  const int d_lo = (bz % ZCH) * DC;

  // zero both raw buffers + zrow (invalid halo stays 0 forever)
  for (int i = tid; i < ZEND; i += 256) sm[i] = 0.f;

  // shared banded selection fragment: SEL[j] = [n15 <= k <= n15+8], k = 8*q4+j
  half8 SEL;
  #pragma unroll
  for (int j = 0; j < 8; ++j) {
    const int k = 8*q4 + j;
    SEL[j] = (k >= n15 && k <= n15 + 8) ? (_Float16)1 : (_Float16)0;
  }

  // ---------- staging: 288 tasks = 2 slc x 24 r x 6 quads ----------
  bool val0 = false, val1 = false;
  int  lo0 = 0, lo1 = 0, sc0 = 0, sc1 = 0;
  const float *pi0 = gI, *pj0 = gJ, *pi1 = gI, *pj1 = gJ;
  {
    auto prep = [&](int t, bool& val, int& lo, int& sc,
                    const float*& pi, const float*& pj) {
      if (t >= 288) { val = false; return; }
      sc = t / 144;
      const int u = t - sc*144;
      const int r = u / 6, c = u - r*6;
      const int gh = h0 - 4 + r, gw = w0 - 4 + 4*c;
      val = ((unsigned)gh < (unsigned)H_) && (gw >= 0) && (gw + 3 < W_);
      lo  = sc*SLS + r*RS + 2*c;
      const long off = ((long)(bb*D_ + (d_lo - 4 + sc))*H_ + gh)*(long)W_ + gw;
      pi = gI + off; pj = gJ + off;
    };
    prep(tid, val0, lo0, sc0, pi0, pj0);
    prep((tid >= 224) ? tid + 32 : 512, val1, lo1, sc1, pi1, pj1);
  }

  // ---------- chain bases: wave Q handles c = Q, Q+4, Q+8 (<10) ----------
  int rb_[3], hb_[3];
  #pragma unroll
  for (int i = 0; i < 3; ++i) {
    int c = Q + 4*i; if (c > 9) c = 9;          // clamped entry unused
    rb_[i] = (c % 5)*FS + (c / 5)*SLS;
    hb_[i] = HSUM0 + c*HCS;
  }
  const int a1r = n15*RS + 4*q4;
  const int a2r = (n15 < 8) ? ((16 + n15)*RS + 4*q4) : -1;
  const int zr  = ZROW + 4*q4;

  // ---------- ring: thread owns (h = tid>>4, w = tid&15) ----------
  const int rh = tid >> 4, rw = tid & 15;
  const int rbase = HSUM0 + rw*HRS + (rh >> 1);
  const int rsh   = (rh & 1) * 16;

  float ring[5][9], S[5];
  #pragma unroll
  for (int f = 0; f < 5; ++f) {
    S[f] = 0.f;
    #pragma unroll
    for (int k = 0; k < 9; ++k) ring[f][k] = 0.f;
  }
  float acc = 0.f;

  // ---------- global prefetch ----------
  float4 f0i = {0,0,0,0}, f0j = {0,0,0,0}, f1i = {0,0,0,0}, f1j = {0,0,0,0};
  auto fetch = [&](int sbase) {
    if (val0 && (unsigned)(sbase + sc0) < (unsigned)D_) {
      f0i = *(const float4*)pi0; f0j = *(const float4*)pj0;
    } else { f0i = make_float4(0,0,0,0); f0j = make_float4(0,0,0,0); }
    pi0 += 2*HW_; pj0 += 2*HW_;
    if (val1 && (unsigned)(sbase + sc1) < (unsigned)D_) {
      f1i = *(const float4*)pi1; f1j = *(const float4*)pj1;
    } else { f1i = make_float4(0,0,0,0); f1j = make_float4(0,0,0,0); }
    pi1 += 2*HW_; pj1 += 2*HW_;
  };

  auto stage_one = [&](int lo, float4 fi, float4 fj) {
    const __half2 i01 = __floats2half2_rn(fi.x, fi.y);
    const __half2 i23 = __floats2half2_rn(fi.z, fi.w);
    const __half2 j01 = __floats2half2_rn(fj.x, fj.y);
    const __half2 j23 = __floats2half2_rn(fj.z, fj.w);
    HP hI; hI.a = i01; hI.b = i23;
    HP hJ; hJ.a = j01; hJ.b = j23;
    HP h2; h2.a = __hmul2(i01, i01); h2.b = __hmul2(i23, i23);
    HP h3; h3.a = __hmul2(j01, j01); h3.b = __hmul2(j23, j23);
    HP h4; h4.a = __hmul2(i01, j01); h4.b = __hmul2(i23, j23);
    *(HP*)&sm[lo]        = hI;
    *(HP*)&sm[lo +   FS] = hJ;
    *(HP*)&sm[lo + 2*FS] = h2;
    *(HP*)&sm[lo + 3*FS] = h3;
    *(HP*)&sm[lo + 4*FS] = h4;
  };
  auto stage_write = [&](int buf) {
    const int b = buf * RAWSZ;
    if (val0) stage_one(b + lo0, f0i, f0j);
    if (val1) stage_one(b + lo1, f1i, f1j);
  };

  // ---- one chain: raw field slice -> hsum (3 MFMAs, transpose in-register) ----
  auto chain = [&](int rb, int hb) {
    const half8 A1 = *(const half8*)&sm[rb + a1r];
    const half8 A2 = (a2r >= 0) ? *(const half8*)&sm[rb + a2r]
                                : *(const half8*)&sm[zr];
    const f32x4 z = {0.f, 0.f, 0.f, 0.f};
    const f32x4 d1 = MFMA16(A1, SEL, z);      // wsum rows 0..15
    const f32x4 d2 = MFMA16(A2, SEL, z);      // wsum rows 16..23 (24..31 = 0)
    unsigned t0 = __builtin_bit_cast(unsigned, __floats2half2_rn(d1[0], d1[1]));
    unsigned t1 = __builtin_bit_cast(unsigned, __floats2half2_rn(d1[2], d1[3]));
    unsigned u0 = __builtin_bit_cast(unsigned, __floats2half2_rn(d2[0], d2[1]));
    unsigned u1 = __builtin_bit_cast(unsigned, __floats2half2_rn(d2[2], d2[3]));
    PL32(t0, u0);
    PL32(t1, u1);
    PL16(t0, u0);
    PL16(t1, u1);
    union { unsigned u[4]; half8 h; } Bv;
    Bv.u[0] = t0; Bv.u[1] = t1; Bv.u[2] = u0; Bv.u[3] = u1;
    const f32x4 dh = MFMA16(SEL, Bv.h, z);    // hsum[m = h][n = w]
    HP ph; ph.a = __floats2half2_rn(dh[0], dh[1]); ph.b = __floats2half2_rn(dh[2], dh[3]);
    *(HP*)&sm[hb + n15*HRS + 2*q4] = ph;      // col w = n15, h = 4q4..4q4+3
  };

  auto h2ext = [&](int addr) -> float {
    const unsigned u = *(const unsigned*)&sm[addr];
    return __half2float(__ushort_as_half((unsigned short)(u >> rsh)));
  };
  auto ring_cc = [&](int m, int hB) {
    float nA[5], nB[5];
    #pragma unroll
    for (int f = 0; f < 5; ++f) {
      nA[f] = h2ext(rbase + hB + f*HCS);      // slice A = chain f
      nB[f] = h2ext(rbase + hB + (5 + f)*HCS);// slice B = chain 5+f
    }
    float SA[5], SB[5];
    #pragma unroll
    for (int f = 0; f < 5; ++f) {
      SA[f] = S[f]  + nA[f] - ring[f][8];
      SB[f] = SA[f] + nB[f] - ring[f][7];
      S[f]  = SB[f];
      #pragma unroll
      for (int k = 8; k >= 2; --k) ring[f][k] = ring[f][k-2];
      ring[f][1] = nA[f]; ring[f][0] = nB[f];
    }
    if (m >= 4) {
      {
        const float cr = SA[4] - SA[0]*SA[1]*W3I;
        const float vi = SA[2] - SA[0]*SA[0]*W3I;
        const float vj = SA[3] - SA[1]*SA[1]*W3I;
        acc += cr*cr * RCP(vi*vj + 1e-5f);
      }
      {
        const float cr = SB[4] - SB[0]*SB[1]*W3I;
        const float vi = SB[2] - SB[0]*SB[0]*W3I;
        const float vj = SB[3] - SB[1]*SB[1]*W3I;
        acc += cr*cr * RCP(vi*vj + 1e-5f);
      }
    }
  };

  fetch(d_lo - 4);          // macro 0 slices
  __syncthreads();          // zero-init visible
  stage_write(0);           // raw macro 0 -> buf 0
  fetch(d_lo - 2);          // macro 1 slices
  __syncthreads();          // raw 0 ready

  // R13 body + PROBE: chain phase duplicated (pass 2 idempotent — same raw
  // inputs, rewrites identical hsum bytes). Memory-fence between passes
  // prevents CSE; marginal dur = chain phase critical-path share.
  for (int m = 0; m < NMAC; ++m) {
    const int rB = (m & 1) * RAWSZ;
    const int hB = (m & 1) * HSZ;
    chain(rB + rb_[0], hB + hb_[0]);
    chain(rB + rb_[1], hB + hb_[1]);
    if (Q < 2) chain(rB + rb_[2], hB + hb_[2]);
    asm volatile("" ::: "memory");         // block CSE of the duplicate pass
    chain(rB + rb_[0], hB + hb_[0]);
    chain(rB + rb_[1], hB + hb_[1]);
    if (Q < 2) chain(rB + rb_[2], hB + hb_[2]);
    if (m + 1 < NMAC) { stage_write((m + 1) & 1); fetch(d_lo + 2*m); }
    __syncthreads();                       // hsum[m&1] + raw[(m+1)&1] ready
    ring_cc(m, hB);                        // overlaps chains(m+1), no barrier
  }

  // ---- block reduction -> single atomic ----
  float v = acc;
  #pragma unroll
  for (int off = 32; off > 0; off >>= 1)
    v += __shfl_down(v, off, 64);
  if (lane == 0) sm[REDU + Q] = v;
  __syncthreads();
  if (tid == 0) {
    const float t = sm[REDU] + sm[REDU+1] + sm[REDU+2] + sm[REDU+3];
    atomicAdd(out, -t / NTOT);
  }
}

extern "C" void kernel_launch(void* const* d_in, const int* in_sizes, int n_in,
                              void* d_out, int out_size, void* d_ws, size_t ws_size,
                              hipStream_t stream) {
  const float* J = (const float*)d_in[0];  // y_pred
  const float* I = (const float*)d_in[1];  // y_true (cc symmetric in I,J)
  float* outp = (float*)d_out;
  hipMemsetAsync(d_out, 0, sizeof(float), stream);
  dim3 grid(W_/16, H_/16, B_*ZCH);         // 10 x 12 x 4 = 480 blocks
  ncc_fused<<<grid, dim3(256), 0, stream>>>(I, J, outp);
}

// Round 10
// 143.104 us; speedup vs baseline: 1.0845x; 1.0845x over previous
//
#include <hip/hip_runtime.h>
#include <hip/hip_fp16.h>

// NCC loss, fully fused, R17: 4-slice macros merged into R13's 1-barrier
// pipeline. R16 probe: chain phase = 553 cyc (~32%) of the 1702-cyc macro,
// and its critical path is 3 chains on waves 0/1 (waves 2/3 do 2 -> convoy).
// R17: 4 slices/macro -> 20 chains = 5/wave BALANCED (per-2-slice path
// 3 -> 2.5 chains), barrier/loop overhead per-2-slice halved, ring shift-by-4.
// Structure = R13 (one barrier/macro, dbuf raw+hsum, ring after barrier
// overlapping next chains); staging = R12's verified 576-task scheme; chain
// = R11 permlane transpose; ring prefix arithmetic verbatim (absmax 0.0).
// LDS 71.8 KB -> 2 blocks/CU (= the 1.875 grid needs; R10: residency beyond
// this is irrelevant). DC=80.
// Vols: [B=2][D=160][H=192][W=160] fp32. Out: scalar -mean(cc).

#define B_    2
#define D_    160
#define H_    192
#define W_    160
#define HW_   (H_*W_)

// LDS layout (float-word offsets)
#define RS    12                   // raw row stride: 24 taps fp16 = 12 dw, packed
#define SLS   (24*RS)              // 288: raw slice stride
#define FS4   (4*SLS)              // 1152: raw field stride (4 slices)
#define RAWSZ (5*FS4)              // 5760: one raw buffer (5 fields x 4 slices)
#define ZROW  (2*RAWSZ)            // 11520: 16 dw of zeros (A2 OOB-row reads)
#define ZEND  (ZROW + 16)          // 11536: end of zero-init region
#define HSUM0 ZEND                 // 11536: hsum buffer 0 (20 chains x 160)
#define HCS   160                  // per-(slc,f) hsum block: 16 cols x 10
#define HRS   10                   // hsum col stride (16 h fp16 = 8 dw, pad->10)
#define HSZ   (20*HCS)             // 3200: one hsum buffer
#define REDU  (HSUM0 + 2*HSZ)      // 17936
#define SMEM  (REDU + 8)           // 17944 dw = 71.8 KB -> 2 blocks/CU
#define DC    80                   // z-chunk depth (grid z = 4)
#define ZCH   (D_/DC)              // 2 z-chunks per batch
#define NMAC  ((DC+8)/4)           // 22 macros x 4 slices
#define W3I   (1.0f/729.0f)
#define NTOT  9830400.0f

#if __has_builtin(__builtin_amdgcn_rcpf)
#define RCP(x) __builtin_amdgcn_rcpf(x)
#else
#define RCP(x) (1.0f/(x))
#endif

typedef _Float16 half8 __attribute__((ext_vector_type(8)));
typedef float    f32x4 __attribute__((ext_vector_type(4)));
typedef unsigned u32x2 __attribute__((ext_vector_type(2)));
#define MFMA16(a,b,c) __builtin_amdgcn_mfma_f32_16x16x32_f16((a),(b),(c),0,0,0)

// permlane swaps: a=VDST, b=VSRC, both updated.
#if __has_builtin(__builtin_amdgcn_permlane32_swap)
#define PL32(a,b) do { u32x2 _s = __builtin_amdgcn_permlane32_swap((a),(b),false,false); \
                       (a)=_s[0]; (b)=_s[1]; } while(0)
#else
#define PL32(a,b) asm volatile("s_nop 1\nv_permlane32_swap_b32 %0, %1" : "+v"(a), "+v"(b))
#endif
#if __has_builtin(__builtin_amdgcn_permlane16_swap)
#define PL16(a,b) do { u32x2 _s = __builtin_amdgcn_permlane16_swap((a),(b),false,false); \
                       (a)=_s[0]; (b)=_s[1]; } while(0)
#else
#define PL16(a,b) asm volatile("s_nop 1\nv_permlane16_swap_b32 %0, %1" : "+v"(a), "+v"(b))
#endif

struct __align__(8) HP { __half2 a, b; };   // 4 fp16 = one b64 LDS word-pair

__global__ __launch_bounds__(256, 4) void ncc_fused(const float* __restrict__ gI,
                                                    const float* __restrict__ gJ,
                                                    float* __restrict__ out)
{
  __shared__ __align__(16) float sm[SMEM];
  const int tid  = threadIdx.x;
  const int lane = tid & 63;
  const int Q    = tid >> 6;
  const int n15  = lane & 15;          // MFMA: A-row m / B-col n / D-col
  const int q4   = lane >> 4;          // MFMA: k-group / D-row quad
  const int w0   = blockIdx.x * 16;
  const int h0   = blockIdx.y * 16;
  const int bz   = blockIdx.z;
  const int bb   = bz / ZCH;
  const int d_lo = (bz % ZCH) * DC;

  // zero both raw buffers + zrow (invalid halo stays 0 forever)
  for (int i = tid; i < ZEND; i += 256) sm[i] = 0.f;

  // shared banded selection fragment: SEL[j] = [n15 <= k <= n15+8], k = 8*q4+j
  half8 SEL;
  #pragma unroll
  for (int j = 0; j < 8; ++j) {
    const int k = 8*q4 + j;
    SEL[j] = (k >= n15 && k <= n15 + 8) ? (_Float16)1 : (_Float16)0;
  }

  // ---------- staging: 576 tasks = 4 slc x 24 r x 6 quads ----------
  // tasks tid, tid+256 prefetched; task tid+512 (tid<64) direct-loaded.
  bool val0 = false, val1 = false, val2 = false;
  int  lo0 = 0, lo1 = 0, lo2 = 0, sc0 = 0, sc1 = 0, sc2 = 0;
  const float *pi0 = gI, *pj0 = gJ, *pi1 = gI, *pj1 = gJ, *pi2 = gI, *pj2 = gJ;
  {
    auto prep = [&](int t, bool& val, int& lo, int& sc,
                    const float*& pi, const float*& pj) {
      if (t >= 576) { val = false; return; }
      sc = t / 144;
      const int u = t - sc*144;
      const int r = u / 6, c = u - r*6;
      const int gh = h0 - 4 + r, gw = w0 - 4 + 4*c;
      val = ((unsigned)gh < (unsigned)H_) && (gw >= 0) && (gw + 3 < W_);
      lo  = sc*SLS + r*RS + 2*c;
      const long off = ((long)(bb*D_ + (d_lo - 4 + sc))*H_ + gh)*(long)W_ + gw;
      pi = gI + off; pj = gJ + off;
    };
    prep(tid,       val0, lo0, sc0, pi0, pj0);
    prep(tid + 256, val1, lo1, sc1, pi1, pj1);
    prep((tid < 64) ? tid + 512 : 576, val2, lo2, sc2, pi2, pj2);
  }

  // ---------- chain bases: wave Q = slice Q, fields i = 0..4 (balanced) ----
  int rb_[5], hb_[5];
  #pragma unroll
  for (int i = 0; i < 5; ++i) {
    rb_[i] = i*FS4 + Q*SLS;                   // field i, slice Q
    hb_[i] = HSUM0 + (Q*5 + i)*HCS;           // hsum block = slice*5 + field
  }
  const int a1r = n15*RS + 4*q4;
  const int a2r = (n15 < 8) ? ((16 + n15)*RS + 4*q4) : -1;
  const int zr  = ZROW + 4*q4;

  // ---------- ring: thread owns (h = tid>>4, w = tid&15) ----------
  const int rh = tid >> 4, rw = tid & 15;
  const int rbase = HSUM0 + rw*HRS + (rh >> 1);
  const int rsh   = (rh & 1) * 16;

  float ring[5][9], S[5];
  #pragma unroll
  for (int f = 0; f < 5; ++f) {
    S[f] = 0.f;
    #pragma unroll
    for (int k = 0; k < 9; ++k) ring[f][k] = 0.f;
  }
  float acc = 0.f;

  // ---------- global prefetch (slots 0,1; slot 2 direct-loads) ----------
  float4 f0i = {0,0,0,0}, f0j = {0,0,0,0}, f1i = {0,0,0,0}, f1j = {0,0,0,0};
  int sb_cur = 0;                     // slice base of the macro being staged
  auto fetch = [&](int sbase) {
    sb_cur = sbase;
    if (val0 && (unsigned)(sbase + sc0) < (unsigned)D_) {
      f0i = *(const float4*)pi0; f0j = *(const float4*)pj0;
    } else { f0i = make_float4(0,0,0,0); f0j = make_float4(0,0,0,0); }
    pi0 += 4*HW_; pj0 += 4*HW_;
    if (val1 && (unsigned)(sbase + sc1) < (unsigned)D_) {
      f1i = *(const float4*)pi1; f1j = *(const float4*)pj1;
    } else { f1i = make_float4(0,0,0,0); f1j = make_float4(0,0,0,0); }
    pi1 += 4*HW_; pj1 += 4*HW_;
  };

  auto stage_one = [&](int lo, float4 fi, float4 fj) {
    const __half2 i01 = __floats2half2_rn(fi.x, fi.y);
    const __half2 i23 = __floats2half2_rn(fi.z, fi.w);
    const __half2 j01 = __floats2half2_rn(fj.x, fj.y);
    const __half2 j23 = __floats2half2_rn(fj.z, fj.w);
    HP hI; hI.a = i01; hI.b = i23;
    HP hJ; hJ.a = j01; hJ.b = j23;
    HP h2; h2.a = __hmul2(i01, i01); h2.b = __hmul2(i23, i23);
    HP h3; h3.a = __hmul2(j01, j01); h3.b = __hmul2(j23, j23);
    HP h4; h4.a = __hmul2(i01, j01); h4.b = __hmul2(i23, j23);
    *(HP*)&sm[lo]         = hI;
    *(HP*)&sm[lo +   FS4] = hJ;
    *(HP*)&sm[lo + 2*FS4] = h2;
    *(HP*)&sm[lo + 3*FS4] = h3;
    *(HP*)&sm[lo + 4*FS4] = h4;
  };
  auto stage_write = [&](int buf) {
    const int b = buf * RAWSZ;
    // slot 2 (wave 0 only): issue loads first, then stage 0,1 under them
    float4 f2i = {0,0,0,0}, f2j = {0,0,0,0};
    const bool do2 = val2 && (unsigned)(sb_cur + sc2) < (unsigned)D_;
    if (do2) { f2i = *(const float4*)pi2; f2j = *(const float4*)pj2; }
    pi2 += 4*HW_; pj2 += 4*HW_;
    if (val0) stage_one(b + lo0, f0i, f0j);
    if (val1) stage_one(b + lo1, f1i, f1j);
    if (val2) stage_one(b + lo2, f2i, f2j);
  };

  // ---- one chain: raw field slice -> hsum (3 MFMAs, transpose in-register) ----
  auto chain = [&](int rb, int hb) {
    const half8 A1 = *(const half8*)&sm[rb + a1r];
    const half8 A2 = (a2r >= 0) ? *(const half8*)&sm[rb + a2r]
                                : *(const half8*)&sm[zr];
    const f32x4 z = {0.f, 0.f, 0.f, 0.f};
    const f32x4 d1 = MFMA16(A1, SEL, z);      // wsum rows 0..15
    const f32x4 d2 = MFMA16(A2, SEL, z);      // wsum rows 16..23 (24..31 = 0)
    unsigned t0 = __builtin_bit_cast(unsigned, __floats2half2_rn(d1[0], d1[1]));
    unsigned t1 = __builtin_bit_cast(unsigned, __floats2half2_rn(d1[2], d1[3]));
    unsigned u0 = __builtin_bit_cast(unsigned, __floats2half2_rn(d2[0], d2[1]));
    unsigned u1 = __builtin_bit_cast(unsigned, __floats2half2_rn(d2[2], d2[3]));
    PL32(t0, u0);
    PL32(t1, u1);
    PL16(t0, u0);
    PL16(t1, u1);
    union { unsigned u[4]; half8 h; } Bv;
    Bv.u[0] = t0; Bv.u[1] = t1; Bv.u[2] = u0; Bv.u[3] = u1;
    const f32x4 dh = MFMA16(SEL, Bv.h, z);    // hsum[m = h][n = w]
    HP ph; ph.a = __floats2half2_rn(dh[0], dh[1]); ph.b = __floats2half2_rn(dh[2], dh[3]);
    *(HP*)&sm[hb + n15*HRS + 2*q4] = ph;      // col w = n15, h = 4q4..4q4+3
  };

  auto h2ext = [&](int addr) -> float {
    const unsigned u = *(const unsigned*)&sm[addr];
    return __half2float(__ushort_as_half((unsigned short)(u >> rsh)));
  };
  auto cc_eval = [&](const float* Sx) {
    const float cr = Sx[4] - Sx[0]*Sx[1]*W3I;
    const float vi = Sx[2] - Sx[0]*Sx[0]*W3I;
    const float vj = Sx[3] - Sx[1]*Sx[1]*W3I;
    acc += cr*cr * RCP(vi*vj + 1e-5f);
  };
  auto ring_cc = [&](int m, int hB) {
    float n0[5], n1[5], n2[5], n3[5];
    #pragma unroll
    for (int f = 0; f < 5; ++f) {
      n0[f] = h2ext(rbase + hB + (     f)*HCS);   // slice 0
      n1[f] = h2ext(rbase + hB + ( 5 + f)*HCS);   // slice 1
      n2[f] = h2ext(rbase + hB + (10 + f)*HCS);   // slice 2
      n3[f] = h2ext(rbase + hB + (15 + f)*HCS);   // slice 3
    }
    float SA[5], SB[5], SC[5], SD[5];
    #pragma unroll
    for (int f = 0; f < 5; ++f) {
      SA[f] = S[f]  + n0[f] - ring[f][8];
      SB[f] = SA[f] + n1[f] - ring[f][7];
      SC[f] = SB[f] + n2[f] - ring[f][6];
      SD[f] = SC[f] + n3[f] - ring[f][5];
      S[f]  = SD[f];
      ring[f][8] = ring[f][4]; ring[f][7] = ring[f][3]; ring[f][6] = ring[f][2];
      ring[f][5] = ring[f][1]; ring[f][4] = ring[f][0];
      ring[f][3] = n0[f]; ring[f][2] = n1[f]; ring[f][1] = n2[f]; ring[f][0] = n3[f];
    }
    if (m >= 2) { cc_eval(SA); cc_eval(SB); cc_eval(SC); cc_eval(SD); }
  };

  // ---------- prologue ----------
  fetch(d_lo - 4);          // macro 0 slices
  __syncthreads();          // zero-init visible
  stage_write(0);           // raw macro 0 -> buf 0
  fetch(d_lo);              // macro 1 slices
  __syncthreads();          // raw 0 ready

  // One barrier per macro (R13 schedule). chains(m) read raw[m&1], write
  // hsum[m&1]; stage(m+1) writes raw[(m+1)&1] (readers finished a barrier
  // ago); post-barrier ring_cc(m) reads hsum[m&1] and overlaps chains(m+1)
  // in other waves (which touch hsum[(m+1)&1]) — all disjoint.
  for (int m = 0; m < NMAC; ++m) {
    const int rB = (m & 1) * RAWSZ;
    const int hB = (m & 1) * HSZ;
    #pragma unroll
    for (int i = 0; i < 5; ++i) chain(rB + rb_[i], hB + hb_[i]);
    if (m + 1 < NMAC) { stage_write((m + 1) & 1); fetch(d_lo + 4 + 4*m); }
    __syncthreads();                       // hsum[m&1] + raw[(m+1)&1] ready
    ring_cc(m, hB);                        // overlaps chains(m+1), no barrier
  }

  // ---- block reduction -> single atomic ----
  float v = acc;
  #pragma unroll
  for (int off = 32; off > 0; off >>= 1)
    v += __shfl_down(v, off, 64);
  if (lane == 0) sm[REDU + Q] = v;
  __syncthreads();
  if (tid == 0) {
    const float t = sm[REDU] + sm[REDU+1] + sm[REDU+2] + sm[REDU+3];
    atomicAdd(out, -t / NTOT);
  }
}

extern "C" void kernel_launch(void* const* d_in, const int* in_sizes, int n_in,
                              void* d_out, int out_size, void* d_ws, size_t ws_size,
                              hipStream_t stream) {
  const float* J = (const float*)d_in[0];  // y_pred
  const float* I = (const float*)d_in[1];  // y_true (cc symmetric in I,J)
  float* outp = (float*)d_out;
  hipMemsetAsync(d_out, 0, sizeof(float), stream);
  dim3 grid(W_/16, H_/16, B_*ZCH);         // 10 x 12 x 4 = 480 blocks
  ncc_fused<<<grid, dim3(256), 0, stream>>>(I, J, outp);
}

// Round 11
// 139.917 us; speedup vs baseline: 1.1092x; 1.0228x over previous
//
#include <hip/hip_runtime.h>
#include <hip/hip_fp16.h>

// NCC loss, fully fused, R19: R13 + split-ring scheduling (hide ring-read
// latency under the chain phase).
// R17 post-mortem: balanced 4-slice macro slightly regressed (743 vs 709
// ns/2-slice) — reverted to R13. Model: ~70% stall at every pipe; macro time
// is a chain of serial LDS round-trips. R13's ring_cc stalls right after the
// barrier: its 10 ds_read_b32 are consumed immediately (h2ext cvt is a use).
// R19 splits ring_cc: ring_load = 10 raw u32 reads into registers (no cvt),
// issued BETWEEN chain 0 and chain 1 of the next macro; ring_fin (cvt +
// prefix + cc, register-only) runs after the last chain — in-order DS return
// completes the ring reads under chain-0 compute. Identical barrier/dbuf
// semantics and arithmetic order as R13 (absmax 0.0). +10 transient VGPR.
// DC=80, one barrier/macro, dbuf raw+hsum, permlane-transpose chains.
// Vols: [B=2][D=160][H=192][W=160] fp32. Out: scalar -mean(cc).

#define B_    2
#define D_    160
#define H_    192
#define W_    160
#define HW_   (H_*W_)

// LDS layout (float-word offsets)
#define RS    12                   // raw row stride: 24 taps fp16 = 12 dw, packed
#define SLS   (24*RS)              // 288: raw slice stride
#define FS    (2*SLS)              // 576: raw field stride (2 slices)
#define RAWSZ (5*FS)               // 2880: one raw buffer (5 fields)
#define ZROW  (2*RAWSZ)            // 5760: 16 dw of zeros (A2 OOB-row reads)
#define ZEND  (ZROW + 16)          // 5776: end of zero-init region
#define HSUM0 ZEND                 // 5776: hsum buffer 0 (10 chains x 160)
#define HCS   160                  // per-(slc,f) hsum block: 16 cols x 10
#define HRS   10                   // hsum col stride (16 h fp16 = 8 dw, pad->10)
#define HSZ   (10*HCS)             // 1600: one hsum buffer
#define REDU  (HSUM0 + 2*HSZ)      // 8976
#define SMEM  (REDU + 8)           // 8984 dw = 35.9 KB
#define DC    80                   // z-chunk depth (grid z = 4)
#define ZCH   (D_/DC)              // 2 z-chunks per batch
#define NMAC  ((DC+8)/2)           // 44 macros x 2 slices
#define W3I   (1.0f/729.0f)
#define NTOT  9830400.0f

#if __has_builtin(__builtin_amdgcn_rcpf)
#define RCP(x) __builtin_amdgcn_rcpf(x)
#else
#define RCP(x) (1.0f/(x))
#endif

typedef _Float16 half8 __attribute__((ext_vector_type(8)));
typedef float    f32x4 __attribute__((ext_vector_type(4)));
typedef unsigned u32x2 __attribute__((ext_vector_type(2)));
#define MFMA16(a,b,c) __builtin_amdgcn_mfma_f32_16x16x32_f16((a),(b),(c),0,0,0)

// permlane swaps: a=VDST, b=VSRC, both updated.
#if __has_builtin(__builtin_amdgcn_permlane32_swap)
#define PL32(a,b) do { u32x2 _s = __builtin_amdgcn_permlane32_swap((a),(b),false,false); \
                       (a)=_s[0]; (b)=_s[1]; } while(0)
#else
#define PL32(a,b) asm volatile("s_nop 1\nv_permlane32_swap_b32 %0, %1" : "+v"(a), "+v"(b))
#endif
#if __has_builtin(__builtin_amdgcn_permlane16_swap)
#define PL16(a,b) do { u32x2 _s = __builtin_amdgcn_permlane16_swap((a),(b),false,false); \
                       (a)=_s[0]; (b)=_s[1]; } while(0)
#else
#define PL16(a,b) asm volatile("s_nop 1\nv_permlane16_swap_b32 %0, %1" : "+v"(a), "+v"(b))
#endif

struct __align__(8) HP { __half2 a, b; };   // 4 fp16 = one b64 LDS word-pair

__global__ __launch_bounds__(256, 4) void ncc_fused(const float* __restrict__ gI,
                                                    const float* __restrict__ gJ,
                                                    float* __restrict__ out)
{
  __shared__ __align__(16) float sm[SMEM];
  const int tid  = threadIdx.x;
  const int lane = tid & 63;
  const int Q    = tid >> 6;
  const int n15  = lane & 15;          // MFMA: A-row m / B-col n / D-col
  const int q4   = lane >> 4;          // MFMA: k-group / D-row quad
  const int w0   = blockIdx.x * 16;
  const int h0   = blockIdx.y * 16;
  const int bz   = blockIdx.z;
  const int bb   = bz / ZCH;
  const int d_lo = (bz % ZCH) * DC;

  // zero both raw buffers + zrow (invalid halo stays 0 forever)
  for (int i = tid; i < ZEND; i += 256) sm[i] = 0.f;

  // shared banded selection fragment: SEL[j] = [n15 <= k <= n15+8], k = 8*q4+j
  half8 SEL;
  #pragma unroll
  for (int j = 0; j < 8; ++j) {
    const int k = 8*q4 + j;
    SEL[j] = (k >= n15 && k <= n15 + 8) ? (_Float16)1 : (_Float16)0;
  }

  // ---------- staging: 288 tasks = 2 slc x 24 r x 6 quads ----------
  bool val0 = false, val1 = false;
  int  lo0 = 0, lo1 = 0, sc0 = 0, sc1 = 0;
  const float *pi0 = gI, *pj0 = gJ, *pi1 = gI, *pj1 = gJ;
  {
    auto prep = [&](int t, bool& val, int& lo, int& sc,
                    const float*& pi, const float*& pj) {
      if (t >= 288) { val = false; return; }
      sc = t / 144;
      const int u = t - sc*144;
      const int r = u / 6, c = u - r*6;
      const int gh = h0 - 4 + r, gw = w0 - 4 + 4*c;
      val = ((unsigned)gh < (unsigned)H_) && (gw >= 0) && (gw + 3 < W_);
      lo  = sc*SLS + r*RS + 2*c;
      const long off = ((long)(bb*D_ + (d_lo - 4 + sc))*H_ + gh)*(long)W_ + gw;
      pi = gI + off; pj = gJ + off;
    };
    prep(tid, val0, lo0, sc0, pi0, pj0);
    prep((tid >= 224) ? tid + 32 : 512, val1, lo1, sc1, pi1, pj1);
  }

  // ---------- chain bases: wave Q handles c = Q, Q+4, Q+8 (<10) ----------
  int rb_[3], hb_[3];
  #pragma unroll
  for (int i = 0; i < 3; ++i) {
    int c = Q + 4*i; if (c > 9) c = 9;          // clamped entry unused
    rb_[i] = (c % 5)*FS + (c / 5)*SLS;
    hb_[i] = HSUM0 + c*HCS;
  }
  const int a1r = n15*RS + 4*q4;
  const int a2r = (n15 < 8) ? ((16 + n15)*RS + 4*q4) : -1;
  const int zr  = ZROW + 4*q4;

  // ---------- ring: thread owns (h = tid>>4, w = tid&15) ----------
  const int rh = tid >> 4, rw = tid & 15;
  const int rbase = HSUM0 + rw*HRS + (rh >> 1);
  const int rsh   = (rh & 1) * 16;

  float ring[5][9], S[5];
  #pragma unroll
  for (int f = 0; f < 5; ++f) {
    S[f] = 0.f;
    #pragma unroll
    for (int k = 0; k < 9; ++k) ring[f][k] = 0.f;
  }
  float acc = 0.f;

  // ---------- global prefetch ----------
  float4 f0i = {0,0,0,0}, f0j = {0,0,0,0}, f1i = {0,0,0,0}, f1j = {0,0,0,0};
  auto fetch = [&](int sbase) {
    if (val0 && (unsigned)(sbase + sc0) < (unsigned)D_) {
      f0i = *(const float4*)pi0; f0j = *(const float4*)pj0;
    } else { f0i = make_float4(0,0,0,0); f0j = make_float4(0,0,0,0); }
    pi0 += 2*HW_; pj0 += 2*HW_;
    if (val1 && (unsigned)(sbase + sc1) < (unsigned)D_) {
      f1i = *(const float4*)pi1; f1j = *(const float4*)pj1;
    } else { f1i = make_float4(0,0,0,0); f1j = make_float4(0,0,0,0); }
    pi1 += 2*HW_; pj1 += 2*HW_;
  };

  auto stage_one = [&](int lo, float4 fi, float4 fj) {
    const __half2 i01 = __floats2half2_rn(fi.x, fi.y);
    const __half2 i23 = __floats2half2_rn(fi.z, fi.w);
    const __half2 j01 = __floats2half2_rn(fj.x, fj.y);
    const __half2 j23 = __floats2half2_rn(fj.z, fj.w);
    HP hI; hI.a = i01; hI.b = i23;
    HP hJ; hJ.a = j01; hJ.b = j23;
    HP h2; h2.a = __hmul2(i01, i01); h2.b = __hmul2(i23, i23);
    HP h3; h3.a = __hmul2(j01, j01); h3.b = __hmul2(j23, j23);
    HP h4; h4.a = __hmul2(i01, j01); h4.b = __hmul2(i23, j23);
    *(HP*)&sm[lo]        = hI;
    *(HP*)&sm[lo +   FS] = hJ;
    *(HP*)&sm[lo + 2*FS] = h2;
    *(HP*)&sm[lo + 3*FS] = h3;
    *(HP*)&sm[lo + 4*FS] = h4;
  };
  auto stage_write = [&](int buf) {
    const int b = buf * RAWSZ;
    if (val0) stage_one(b + lo0, f0i, f0j);
    if (val1) stage_one(b + lo1, f1i, f1j);
  };

  // ---- one chain: raw field slice -> hsum (3 MFMAs, transpose in-register) ----
  auto chain = [&](int rb, int hb) {
    const half8 A1 = *(const half8*)&sm[rb + a1r];
    const half8 A2 = (a2r >= 0) ? *(const half8*)&sm[rb + a2r]
                                : *(const half8*)&sm[zr];
    const f32x4 z = {0.f, 0.f, 0.f, 0.f};
    const f32x4 d1 = MFMA16(A1, SEL, z);      // wsum rows 0..15
    const f32x4 d2 = MFMA16(A2, SEL, z);      // wsum rows 16..23 (24..31 = 0)
    unsigned t0 = __builtin_bit_cast(unsigned, __floats2half2_rn(d1[0], d1[1]));
    unsigned t1 = __builtin_bit_cast(unsigned, __floats2half2_rn(d1[2], d1[3]));
    unsigned u0 = __builtin_bit_cast(unsigned, __floats2half2_rn(d2[0], d2[1]));
    unsigned u1 = __builtin_bit_cast(unsigned, __floats2half2_rn(d2[2], d2[3]));
    PL32(t0, u0);
    PL32(t1, u1);
    PL16(t0, u0);
    PL16(t1, u1);
    union { unsigned u[4]; half8 h; } Bv;
    Bv.u[0] = t0; Bv.u[1] = t1; Bv.u[2] = u0; Bv.u[3] = u1;
    const f32x4 dh = MFMA16(SEL, Bv.h, z);    // hsum[m = h][n = w]
    HP ph; ph.a = __floats2half2_rn(dh[0], dh[1]); ph.b = __floats2half2_rn(dh[2], dh[3]);
    *(HP*)&sm[hb + n15*HRS + 2*q4] = ph;      // col w = n15, h = 4q4..4q4+3
  };

  // ---- split ring: load raw u32s early (no cvt -> no forced waitcnt), ----
  // ---- finish (cvt + prefix + cc, register-only) after the chains.      ----
  auto ring_load = [&](int hB, unsigned* ra, unsigned* rb2) {
    #pragma unroll
    for (int f = 0; f < 5; ++f) {
      ra[f]  = *(const unsigned*)&sm[rbase + hB + f*HCS];        // slice A
      rb2[f] = *(const unsigned*)&sm[rbase + hB + (5 + f)*HCS];  // slice B
    }
  };
  auto ring_fin = [&](int mm, const unsigned* ra, const unsigned* rb2) {
    float nA[5], nB[5];
    #pragma unroll
    for (int f = 0; f < 5; ++f) {
      nA[f] = __half2float(__ushort_as_half((unsigned short)(ra[f]  >> rsh)));
      nB[f] = __half2float(__ushort_as_half((unsigned short)(rb2[f] >> rsh)));
    }
    float SA[5], SB[5];
    #pragma unroll
    for (int f = 0; f < 5; ++f) {
      SA[f] = S[f]  + nA[f] - ring[f][8];
      SB[f] = SA[f] + nB[f] - ring[f][7];
      S[f]  = SB[f];
      #pragma unroll
      for (int k = 8; k >= 2; --k) ring[f][k] = ring[f][k-2];
      ring[f][1] = nA[f]; ring[f][0] = nB[f];
    }
    if (mm >= 4) {
      {
        const float cr = SA[4] - SA[0]*SA[1]*W3I;
        const float vi = SA[2] - SA[0]*SA[0]*W3I;
        const float vj = SA[3] - SA[1]*SA[1]*W3I;
        acc += cr*cr * RCP(vi*vj + 1e-5f);
      }
      {
        const float cr = SB[4] - SB[0]*SB[1]*W3I;
        const float vi = SB[2] - SB[0]*SB[0]*W3I;
        const float vj = SB[3] - SB[1]*SB[1]*W3I;
        acc += cr*cr * RCP(vi*vj + 1e-5f);
      }
    }
  };

  fetch(d_lo - 4);          // macro 0 slices
  __syncthreads();          // zero-init visible
  stage_write(0);           // raw macro 0 -> buf 0
  fetch(d_lo - 2);          // macro 1 slices
  __syncthreads();          // raw 0 ready

  // macro 0 (nothing to ring yet) — identical to R13's iteration 0 pre-ring
  chain(rb_[0], hb_[0]);
  chain(rb_[1], hb_[1]);
  if (Q < 2) chain(rb_[2], hb_[2]);
  stage_write(1);           // raw macro 1 (set fetched in prologue)
  fetch(d_lo + 0);          // macro 2 slices
  __syncthreads();          // hsum[0] + raw[1] ready

  // Steady state: ring(m-1) is loaded between chain 0 and chain 1 of macro m
  // (in-order DS return completes the 10 reads under chain-0 compute) and
  // finished after the last chain. Barrier/dbuf semantics identical to R13:
  // ring(m-1) reads hsum[(m-1)&1]; chains(m) write hsum[m&1]; stage(m+1)
  // writes raw[(m+1)&1] whose readers finished a barrier ago.
  for (int m = 1; m < NMAC; ++m) {
    const int rB = (m & 1) * RAWSZ;
    const int hB = (m & 1) * HSZ;
    const int hP = ((m - 1) & 1) * HSZ;
    unsigned rgA[5], rgB[5];
    chain(rB + rb_[0], hB + hb_[0]);
    ring_load(hP, rgA, rgB);
    chain(rB + rb_[1], hB + hb_[1]);
    if (Q < 2) chain(rB + rb_[2], hB + hb_[2]);
    ring_fin(m - 1, rgA, rgB);
    if (m + 1 < NMAC) { stage_write((m + 1) & 1); fetch(d_lo + 2*m); }
    __syncthreads();                       // hsum[m&1] + raw[(m+1)&1] ready
  }
  {                                        // epilogue: last macro's ring
    unsigned rgA[5], rgB[5];
    ring_load(((NMAC - 1) & 1) * HSZ, rgA, rgB);
    ring_fin(NMAC - 1, rgA, rgB);
  }

  // ---- block reduction -> single atomic ----
  float v = acc;
  #pragma unroll
  for (int off = 32; off > 0; off >>= 1)
    v += __shfl_down(v, off, 64);
  if (lane == 0) sm[REDU + Q] = v;
  __syncthreads();
  if (tid == 0) {
    const float t = sm[REDU] + sm[REDU+1] + sm[REDU+2] + sm[REDU+3];
    atomicAdd(out, -t / NTOT);
  }
}

extern "C" void kernel_launch(void* const* d_in, const int* in_sizes, int n_in,
                              void* d_out, int out_size, void* d_ws, size_t ws_size,
                              hipStream_t stream) {
  const float* J = (const float*)d_in[0];  // y_pred
  const float* I = (const float*)d_in[1];  // y_true (cc symmetric in I,J)
  float* outp = (float*)d_out;
  hipMemsetAsync(d_out, 0, sizeof(float), stream);
  dim3 grid(W_/16, H_/16, B_*ZCH);         // 10 x 12 x 4 = 480 blocks
  ncc_fused<<<grid, dim3(256), 0, stream>>>(I, J, outp);
}